// Round 1
// baseline (465.205 us; speedup 1.0000x reference)
//
#include <hip/hip_runtime.h>

#define BATCH 32
#define CDIM 256
#define HW 1024            // 32*32
#define NROWS 32768        // BATCH*HW
#define KCODES 1024
#define ZQ_ELEMS 8388608   // 32*256*1024
#define IDX_OFF ZQ_ELEMS
#define LOSS_OFF (ZQ_ELEMS + NROWS)

// ---- numpy-bit-exact pairwise sum of squares over 256 contiguous floats ----
// numpy pairwise_sum: n=256 -> left(128)+right(128); each 128 uses 8 accumulators
// r[j] = a[j]; for i=8..120 step 8: r[j]+=a[i+j]; combine ((r0+r1)+(r2+r3))+((r4+r5)+(r6+r7))
__device__ __forceinline__ float np_sumsq_256(const float* __restrict__ a) {
    float half[2];
#pragma unroll
    for (int h = 0; h < 2; ++h) {
        const float* p = a + h * 128;
        float r[8];
#pragma unroll
        for (int j = 0; j < 8; ++j) r[j] = __fmul_rn(p[j], p[j]);
#pragma unroll
        for (int i = 8; i < 128; i += 8) {
#pragma unroll
            for (int j = 0; j < 8; ++j)
                r[j] = __fadd_rn(r[j], __fmul_rn(p[i + j], p[i + j]));
        }
        float ta = __fadd_rn(__fadd_rn(r[0], r[1]), __fadd_rn(r[2], r[3]));
        float tb = __fadd_rn(__fadd_rn(r[4], r[5]), __fadd_rn(r[6], r[7]));
        half[h] = __fadd_rn(ta, tb);
    }
    return __fadd_rn(half[0], half[1]);
}

// ---- kernel 1: e2[k] = np-exact sum(emb[k,:]**2) ----
__global__ void e2_kernel(const float* __restrict__ emb, float* __restrict__ e2) {
    int k = blockIdx.x * blockDim.x + threadIdx.x;
    if (k >= KCODES) return;
    e2[k] = np_sumsq_256(emb + (size_t)k * CDIM);
}

// ---- kernel 2: fused distance + argmin ----
// Block: 256 threads handles 32 rows x all 1024 codes.
// tx = t&31 (k dim), ty = t>>5 (m dim); thread tile 4 rows (m=ty+8i) x 4 ks (k=k0+tx+32j)
__global__ void __launch_bounds__(256)
argmin_kernel(const float* __restrict__ z, const float* __restrict__ emb,
              const float* __restrict__ e2g, float* __restrict__ out_idx_f,
              int* __restrict__ ws_idx) {
    __shared__ __align__(16) float z_lds[32 * 260];   // [m][c], stride 260 (pad)
    __shared__ __align__(16) float e_lds[128 * 36];   // [k][c-chunk 32], stride 36 (pad)
    __shared__ float z2_lds[32];

    const int t  = threadIdx.x;
    const int tx = t & 31;
    const int ty = t >> 5;
    const int n0 = blockIdx.x * 32;
    const int b  = n0 >> 10;
    const int hw0 = n0 & 1023;
    const float* zbase = z + (size_t)b * (CDIM * HW) + hw0;

    // stage z tile [32 hw][256 c] -> z_lds[m][c] (float4 along hw, transposed store)
#pragma unroll
    for (int p = 0; p < 8; ++p) {
        int id = p * 256 + t;        // 0..2047 float4s
        int c  = id >> 3;            // 0..255
        int m4 = id & 7;             // 4-float group along hw
        float4 v = *(const float4*)(zbase + (size_t)c * HW + m4 * 4);
        z_lds[(m4 * 4 + 0) * 260 + c] = v.x;
        z_lds[(m4 * 4 + 1) * 260 + c] = v.y;
        z_lds[(m4 * 4 + 2) * 260 + c] = v.z;
        z_lds[(m4 * 4 + 3) * 260 + c] = v.w;
    }
    __syncthreads();

    // np-exact z2 per row (from LDS)
    if (t < 32) z2_lds[t] = np_sumsq_256(&z_lds[t * 260]);
    __syncthreads();

    float z2r[4];
#pragma unroll
    for (int i = 0; i < 4; ++i) z2r[i] = z2_lds[ty + 8 * i];

    float best_s[4];
    int   best_k[4];
#pragma unroll
    for (int i = 0; i < 4; ++i) { best_s[i] = 3.402823466e+38f; best_k[i] = 0; }

    for (int kc = 0; kc < 8; ++kc) {
        const int k0 = kc * 128;
        float acc[4][4];
#pragma unroll
        for (int i = 0; i < 4; ++i)
#pragma unroll
            for (int j = 0; j < 4; ++j) acc[i][j] = 0.f;

        for (int cc = 0; cc < 8; ++cc) {
            const int c0 = cc * 32;
            // stage emb tile: 128 k x 32 c
#pragma unroll
            for (int p = 0; p < 4; ++p) {
                int id = p * 256 + t;     // 0..1023 float4s
                int kl = id >> 3;         // 0..127
                int c4 = id & 7;          // 0..7
                float4 v = *(const float4*)(emb + (size_t)(k0 + kl) * CDIM + c0 + c4 * 4);
                *(float4*)&e_lds[kl * 36 + c4 * 4] = v;
            }
            __syncthreads();

#pragma unroll
            for (int s = 0; s < 8; ++s) {
                float4 zf[4], ef[4];
#pragma unroll
                for (int i = 0; i < 4; ++i)
                    zf[i] = *(const float4*)&z_lds[(ty + 8 * i) * 260 + c0 + s * 4];
#pragma unroll
                for (int j = 0; j < 4; ++j)
                    ef[j] = *(const float4*)&e_lds[(tx + 32 * j) * 36 + s * 4];
#pragma unroll
                for (int i = 0; i < 4; ++i)
#pragma unroll
                    for (int j = 0; j < 4; ++j) {
                        acc[i][j] = fmaf(zf[i].x, ef[j].x, acc[i][j]);
                        acc[i][j] = fmaf(zf[i].y, ef[j].y, acc[i][j]);
                        acc[i][j] = fmaf(zf[i].z, ef[j].z, acc[i][j]);
                        acc[i][j] = fmaf(zf[i].w, ef[j].w, acc[i][j]);
                    }
            }
            __syncthreads();
        }

        // epilogue: d = fl(fl(z2 + e2) - 2*dot), ascending k => strict < keeps first index
        float e2k[4];
#pragma unroll
        for (int j = 0; j < 4; ++j) e2k[j] = e2g[k0 + tx + 32 * j];
#pragma unroll
        for (int j = 0; j < 4; ++j) {
            const int kk = k0 + tx + 32 * j;
#pragma unroll
            for (int i = 0; i < 4; ++i) {
                float t1 = __fadd_rn(z2r[i], e2k[j]);
                float ta = acc[i][j] + acc[i][j];   // 2*dot exact
                float d  = __fsub_rn(t1, ta);
                if (d < best_s[i]) { best_s[i] = d; best_k[i] = kk; }
            }
        }
    }

    // cross-thread reduce (32 tx per row), tie -> lowest k
    __syncthreads();
    float* red_s = e_lds;                  // 1024 floats
    int*   red_k = (int*)(e_lds + 1024);   // 1024 ints
#pragma unroll
    for (int i = 0; i < 4; ++i) {
        int m = ty + 8 * i;
        red_s[m * 32 + tx] = best_s[i];
        red_k[m * 32 + tx] = best_k[i];
    }
    __syncthreads();
    if (t < 32) {
        float bs = 3.402823466e+38f;
        int bk = KCODES;
        for (int x2 = 0; x2 < 32; ++x2) {
            float s = red_s[t * 32 + x2];
            int   k2 = red_k[t * 32 + x2];
            if (s < bs || (s == bs && k2 < bk)) { bs = s; bk = k2; }
        }
        out_idx_f[n0 + t] = (float)bk;   // indices as float (out buffer is fp32)
        ws_idx[n0 + t] = bk;
    }
}

// ---- kernel 3: gather z_q, write z_q_st = z + (z_q - z), partial loss sums ----
__global__ void __launch_bounds__(256)
gather_kernel(const float* __restrict__ z, const float* __restrict__ emb,
              const int* __restrict__ ws_idx, float* __restrict__ out_zq,
              float* __restrict__ partials) {
    const int t   = threadIdx.x;
    const int b   = blockIdx.x >> 3;
    const int hw0 = (blockIdx.x & 7) * 128;
    const int hw  = hw0 + (t & 127);
    const int chalf = t >> 7;   // 0 or 1; thread covers c = 2*ci + chalf

    const int idx = ws_idx[b * HW + hw];
    const float* erow = emb + (size_t)idx * CDIM;
    const float* zb = z + (size_t)b * (CDIM * HW) + hw;
    float* ob = out_zq + (size_t)b * (CDIM * HW) + hw;

    float lsum = 0.f;
    for (int ci = 0; ci < 128; ++ci) {
        int c = 2 * ci + chalf;
        float e  = erow[c];
        float zv = zb[(size_t)c * HW];
        float d  = e - zv;
        ob[(size_t)c * HW] = zv + d;      // straight-through forward value
        lsum = fmaf(d, d, lsum);
    }
    // block reduce
#pragma unroll
    for (int off = 32; off > 0; off >>= 1) lsum += __shfl_down(lsum, off);
    __shared__ float wsum[4];
    if ((t & 63) == 0) wsum[t >> 6] = lsum;
    __syncthreads();
    if (t == 0) partials[blockIdx.x] = (wsum[0] + wsum[1]) + (wsum[2] + wsum[3]);
}

// ---- kernel 4: finalize loss = 1.25 * mean(diff^2) ----
__global__ void loss_kernel(const float* __restrict__ partials, float* __restrict__ out_loss) {
    const int t = threadIdx.x;
    float v = partials[t];   // 256 partials
#pragma unroll
    for (int off = 32; off > 0; off >>= 1) v += __shfl_down(v, off);
    __shared__ float wsum[4];
    if ((t & 63) == 0) wsum[t >> 6] = v;
    __syncthreads();
    if (t == 0) {
        float total = (wsum[0] + wsum[1]) + (wsum[2] + wsum[3]);
        out_loss[0] = 1.25f * total / 8388608.0f;
    }
}

extern "C" void kernel_launch(void* const* d_in, const int* in_sizes, int n_in,
                              void* d_out, int out_size, void* d_ws, size_t ws_size,
                              hipStream_t stream) {
    const float* z   = (const float*)d_in[0];
    const float* emb = (const float*)d_in[1];
    float* out = (float*)d_out;

    float* e2       = (float*)d_ws;                                   // 1024 f
    int*   ws_idx   = (int*)((char*)d_ws + 4096);                     // 32768 i32
    float* partials = (float*)((char*)d_ws + 4096 + 131072);          // 256 f

    hipLaunchKernelGGL(e2_kernel, dim3(4), dim3(256), 0, stream, emb, e2);
    hipLaunchKernelGGL(argmin_kernel, dim3(1024), dim3(256), 0, stream,
                       z, emb, e2, out + IDX_OFF, ws_idx);
    hipLaunchKernelGGL(gather_kernel, dim3(256), dim3(256), 0, stream,
                       z, emb, ws_idx, out, partials);
    hipLaunchKernelGGL(loss_kernel, dim3(1), dim3(256), 0, stream,
                       partials, out + LOSS_OFF);
}